// Round 1
// baseline (922.389 us; speedup 1.0000x reference)
//
#include <hip/hip_runtime.h>
#include <math.h>

#define T_TOK 1024
#define E_EXP 8
#define H_DIM 2880
#define I_DIM 2880
#define NGU   5760      // 2*I
#define KB    90        // 2880/32
#define TM 128
#define TN 128
#define MAXROWS 3072

typedef __attribute__((ext_vector_type(8))) short short8;
typedef __attribute__((ext_vector_type(4))) float f32x4;

// ---- workspace layout (bytes) ----
#define XQ_OFF   0ull                    // T*H bf16 = 5898240
#define ACT_OFF  5898240ull              // MAXROWS*I bf16 = 17694720
#define RTOK_OFF 23592960ull             // MAXROWS int
#define RW_OFF   23605248ull             // MAXROWS float
#define EB_OFF   23617536ull             // 8 int
#define EPC_OFF  23617600ull             // 8 int

__device__ inline ushort f2bf(float f) {
  unsigned u = __float_as_uint(f);
  unsigned r = u + 0x7FFFu + ((u >> 16) & 1u);
  return (ushort)(r >> 16);
}

// e = clip(ceil(log2(max(amax,1e-12))), -127, 128)
__device__ inline int blk_exp(float amax) {
  amax = fmaxf(amax, 1e-12f);
  unsigned b = __float_as_uint(amax);
  int e = (int)(b >> 23) - 127;
  if (b & 0x7FFFFFu) e += 1;
  return min(max(e, -127), 128);
}

// quantize v*2^-eblk to fp8 e4m3 (RNE, subnormal lsb 2^-9), dequantize back.
__device__ inline float qdq_val(float v, int eblk) {
  float av = fabsf(v);
  if (av == 0.f) return 0.f;
  int fl = (int)(__float_as_uint(av) >> 23) - 127 - eblk;  // floor(log2|v/2^eblk|)
  int p = max(fl, -6) - 3;
  float step = ldexpf(1.f, p + eblk);
  return rintf(v / step) * step;
}

__device__ inline float fp4v(int n) {
  int mag = n & 7;
  float v;
  if (mag == 0) v = 0.f;
  else if (mag == 1) v = 0.5f;
  else v = ldexpf(1.0f + 0.5f * (float)(mag & 1), (mag >> 1) - 1);
  return (n & 8) ? -v : v;
}

// ---------------- kernel 1: mxfp8 qdq of hidden_states -> bf16 ----------------
// one thread = 4 floats; 8 consecutive lanes = one 32-value MX block.
__global__ void quant_x_kernel(const float* __restrict__ x, ushort* __restrict__ xq) {
  int g = blockIdx.x * 256 + threadIdx.x;   // 737280 threads total, exact
  float4 v4 = ((const float4*)x)[g];
  float am = fmaxf(fmaxf(fabsf(v4.x), fabsf(v4.y)), fmaxf(fabsf(v4.z), fabsf(v4.w)));
  am = fmaxf(am, __shfl_xor(am, 1));
  am = fmaxf(am, __shfl_xor(am, 2));
  am = fmaxf(am, __shfl_xor(am, 4));
  int eb = blk_exp(am);
  ushort4 o;
  o.x = f2bf(qdq_val(v4.x, eb));
  o.y = f2bf(qdq_val(v4.y, eb));
  o.z = f2bf(qdq_val(v4.z, eb));
  o.w = f2bf(qdq_val(v4.w, eb));
  ((ushort4*)xq)[g] = o;
}

// ---------------- kernel 2: routing -> per-expert padded row lists ----------------
__global__ void routing_kernel(const int* __restrict__ eidx, const float* __restrict__ rwt,
                               int* __restrict__ rtok, float* __restrict__ rw,
                               int* __restrict__ ebase, int* __restrict__ epc) {
  __shared__ int cnt[E_EXP];
  __shared__ int base_s[E_EXP];
  __shared__ int pos[E_EXP];
  int t = threadIdx.x;
  if (t < E_EXP) cnt[t] = 0;
  __syncthreads();
  for (int p = t; p < T_TOK * 2; p += 256) atomicAdd(&cnt[eidx[p]], 1);
  __syncthreads();
  if (t == 0) {
    int b = 0;
    for (int e = 0; e < E_EXP; e++) {
      base_s[e] = b;
      b += ((cnt[e] + TM - 1) / TM) * TM;
    }
  }
  __syncthreads();
  if (t < E_EXP) {
    pos[t] = 0;
    ebase[t] = base_s[t];
    epc[t] = ((cnt[t] + TM - 1) / TM) * TM;
  }
  __syncthreads();
  for (int p = t; p < T_TOK * 2; p += 256) {
    int e = eidx[p];
    int o = atomicAdd(&pos[e], 1);
    rtok[base_s[e] + o] = p >> 1;
    rw[base_s[e] + o] = rwt[p];
  }
  __syncthreads();
  for (int e = 0; e < E_EXP; e++) {
    int c = cnt[e], pc = ((c + TM - 1) / TM) * TM;
    for (int i = c + t; i < pc; i += 256) {
      rtok[base_s[e] + i] = 0;
      rw[base_s[e] + i] = 0.f;
    }
  }
}

// ---------------- kernel 3: GEMM1 (xq @ Wgu^T + b) -> swiglu -> qdq -> act ----------------
__global__ __launch_bounds__(256, 2)
void gemm1_kernel(const ushort* __restrict__ xq,
                  const int* __restrict__ gub, const int* __restrict__ gus,
                  const float* __restrict__ gubias,
                  const int* __restrict__ rtok, const int* __restrict__ ebase,
                  const int* __restrict__ epc,
                  ushort* __restrict__ act) {
  const int ntile = blockIdx.x;           // 0..44
  const int e = blockIdx.y >> 4;
  const int mtile = blockIdx.y & 15;
  if (mtile * TM >= epc[e]) return;
  const int rowbase = ebase[e] + mtile * TM;

  __shared__ __align__(16) ushort lA[TM][40];   // +8 pad: conflict-free b128, 16B-aligned rows
  __shared__ __align__(16) ushort lB[TN][40];
  __shared__ float2 lut[256];

  const int tid = threadIdx.x;
  lut[tid] = make_float2(fp4v(tid & 15), fp4v((tid >> 4) & 15));
  __syncthreads();

  const int wave = tid >> 6, lane = tid & 63;
  const int half = tid & 1, srow = tid >> 1;
  const int wm = (wave & 1) * 64, wn = (wave >> 1) * 64;
  const int lrow = lane & 15, q = lane >> 4;

  const int tokA = rtok[rowbase + srow];
  const ushort* aSrc = xq + tokA * H_DIM + half * 16;
  const int nrow = ntile * TN + srow;                       // < 5760 always
  const int* bSrc = gub + ((e * NGU + nrow) * KB) * 16 + half * 8;
  const int* sSrc = gus + (e * NGU + nrow) * KB;

  f32x4 acc[4][4];
#pragma unroll
  for (int i = 0; i < 4; i++)
#pragma unroll
    for (int j = 0; j < 4; j++) acc[i][j] = (f32x4){0.f, 0.f, 0.f, 0.f};

  for (int kb = 0; kb < KB; kb++) {
    uint4 a0 = ((const uint4*)(aSrc + kb * 32))[0];
    uint4 a1 = ((const uint4*)(aSrc + kb * 32))[1];
    int4 b0 = ((const int4*)(bSrc + kb * 16))[0];
    int4 b1 = ((const int4*)(bSrc + kb * 16))[1];
    float sc = ldexpf(1.f, sSrc[kb] - 127);

    int bv[8] = {b0.x, b0.y, b0.z, b0.w, b1.x, b1.y, b1.z, b1.w};
    uint us[8];
#pragma unroll
    for (int j = 0; j < 8; j++) {
      float2 l = lut[bv[j] & 255];
      us[j] = (uint)f2bf(l.x * sc) | ((uint)f2bf(l.y * sc) << 16);
    }
    __syncthreads();
    *(uint4*)&lA[srow][half * 16] = a0;
    *(uint4*)&lA[srow][half * 16 + 8] = a1;
    uint4 w0; w0.x = us[0]; w0.y = us[1]; w0.z = us[2]; w0.w = us[3];
    uint4 w1; w1.x = us[4]; w1.y = us[5]; w1.z = us[6]; w1.w = us[7];
    *(uint4*)&lB[srow][half * 16] = w0;
    *(uint4*)&lB[srow][half * 16 + 8] = w1;
    __syncthreads();

    short8 af[4], bfr[4];
#pragma unroll
    for (int mi = 0; mi < 4; mi++) af[mi] = *(const short8*)&lA[wm + mi * 16 + lrow][q * 8];
#pragma unroll
    for (int ni = 0; ni < 4; ni++) bfr[ni] = *(const short8*)&lB[wn + ni * 16 + lrow][q * 8];
#pragma unroll
    for (int mi = 0; mi < 4; mi++)
#pragma unroll
      for (int ni = 0; ni < 4; ni++)
        acc[mi][ni] = __builtin_amdgcn_mfma_f32_16x16x32_bf16(af[mi], bfr[ni], acc[mi][ni], 0, 0, 0);
  }

  // epilogue: bias -> swiglu (even n = gate, odd n = up) -> per-32-channel mxfp8 qdq -> act bf16
  const int nbase = ntile * TN + wn;
  float bias_v[4];
#pragma unroll
  for (int ni = 0; ni < 4; ni++) bias_v[ni] = gubias[e * NGU + nbase + ni * 16 + lrow];
  const bool evenl = (lane & 1) == 0;
#pragma unroll
  for (int mi = 0; mi < 4; mi++) {
    float av[4][4];
#pragma unroll
    for (int ni = 0; ni < 4; ni++)
#pragma unroll
      for (int r = 0; r < 4; r++) {
        float h = acc[mi][ni][r] + bias_v[ni];
        float pp = __shfl_xor(h, 1);
        float gate = evenl ? h : pp;
        float up = evenl ? pp : h;
        gate = fminf(gate, 7.f);
        up = fminf(fmaxf(up, -7.f), 7.f);
        float glu = gate / (1.f + expf(-1.702f * gate));
        av[ni][r] = (up + 1.f) * glu;
      }
#pragma unroll
    for (int r = 0; r < 4; r++) {
      float am = 0.f;
#pragma unroll
      for (int ni = 0; ni < 4; ni++) am = fmaxf(am, fabsf(av[ni][r]));
      am = fmaxf(am, __shfl_xor(am, 2));
      am = fmaxf(am, __shfl_xor(am, 4));
      am = fmaxf(am, __shfl_xor(am, 8));
      int eb = blk_exp(am);
      if (evenl) {
        int row = rowbase + wm + mi * 16 + q * 4 + r;
        int cb = (nbase >> 1) + (lrow >> 1);
#pragma unroll
        for (int ni = 0; ni < 4; ni++)
          act[row * I_DIM + cb + ni * 8] = f2bf(qdq_val(av[ni][r], eb));
      }
    }
  }
}

// ---------------- kernel 4: GEMM2 (act @ Wd^T + b) * routing_weight -> atomic scatter ----------------
__global__ __launch_bounds__(256, 2)
void gemm2_kernel(const ushort* __restrict__ act,
                  const int* __restrict__ db, const int* __restrict__ dsc,
                  const float* __restrict__ dbias,
                  const int* __restrict__ rtok, const float* __restrict__ rw,
                  const int* __restrict__ ebase, const int* __restrict__ epc,
                  float* __restrict__ out) {
  const int ntile = blockIdx.x;           // 0..22
  const int e = blockIdx.y >> 4;
  const int mtile = blockIdx.y & 15;
  if (mtile * TM >= epc[e]) return;
  const int rowbase = ebase[e] + mtile * TM;

  __shared__ __align__(16) ushort lA[TM][40];
  __shared__ __align__(16) ushort lB[TN][40];
  __shared__ float2 lut[256];

  const int tid = threadIdx.x;
  lut[tid] = make_float2(fp4v(tid & 15), fp4v((tid >> 4) & 15));
  __syncthreads();

  const int wave = tid >> 6, lane = tid & 63;
  const int half = tid & 1, srow = tid >> 1;
  const int wm = (wave & 1) * 64, wn = (wave >> 1) * 64;
  const int lrow = lane & 15, q = lane >> 4;

  const ushort* aSrc = act + (rowbase + srow) * I_DIM + half * 16;
  int nrow = ntile * TN + srow;
  if (nrow >= H_DIM) nrow = H_DIM - 1;    // clamp loads; stores guarded
  const int* bSrc = db + ((e * H_DIM + nrow) * KB) * 16 + half * 8;
  const int* sSrc = dsc + (e * H_DIM + nrow) * KB;

  f32x4 acc[4][4];
#pragma unroll
  for (int i = 0; i < 4; i++)
#pragma unroll
    for (int j = 0; j < 4; j++) acc[i][j] = (f32x4){0.f, 0.f, 0.f, 0.f};

  for (int kb = 0; kb < KB; kb++) {
    uint4 a0 = ((const uint4*)(aSrc + kb * 32))[0];
    uint4 a1 = ((const uint4*)(aSrc + kb * 32))[1];
    int4 b0 = ((const int4*)(bSrc + kb * 16))[0];
    int4 b1 = ((const int4*)(bSrc + kb * 16))[1];
    float sc = ldexpf(1.f, sSrc[kb] - 127);

    int bv[8] = {b0.x, b0.y, b0.z, b0.w, b1.x, b1.y, b1.z, b1.w};
    uint us[8];
#pragma unroll
    for (int j = 0; j < 8; j++) {
      float2 l = lut[bv[j] & 255];
      us[j] = (uint)f2bf(l.x * sc) | ((uint)f2bf(l.y * sc) << 16);
    }
    __syncthreads();
    *(uint4*)&lA[srow][half * 16] = a0;
    *(uint4*)&lA[srow][half * 16 + 8] = a1;
    uint4 w0; w0.x = us[0]; w0.y = us[1]; w0.z = us[2]; w0.w = us[3];
    uint4 w1; w1.x = us[4]; w1.y = us[5]; w1.z = us[6]; w1.w = us[7];
    *(uint4*)&lB[srow][half * 16] = w0;
    *(uint4*)&lB[srow][half * 16 + 8] = w1;
    __syncthreads();

    short8 af[4], bfr[4];
#pragma unroll
    for (int mi = 0; mi < 4; mi++) af[mi] = *(const short8*)&lA[wm + mi * 16 + lrow][q * 8];
#pragma unroll
    for (int ni = 0; ni < 4; ni++) bfr[ni] = *(const short8*)&lB[wn + ni * 16 + lrow][q * 8];
#pragma unroll
    for (int mi = 0; mi < 4; mi++)
#pragma unroll
      for (int ni = 0; ni < 4; ni++)
        acc[mi][ni] = __builtin_amdgcn_mfma_f32_16x16x32_bf16(af[mi], bfr[ni], acc[mi][ni], 0, 0, 0);
  }

  const int nbase = ntile * TN + wn;
  float bias_v[4];
#pragma unroll
  for (int ni = 0; ni < 4; ni++) {
    int n = nbase + ni * 16 + lrow;
    bias_v[ni] = (n < H_DIM) ? dbias[e * H_DIM + n] : 0.f;
  }
#pragma unroll
  for (int mi = 0; mi < 4; mi++)
#pragma unroll
    for (int r = 0; r < 4; r++) {
      int orow = rowbase + wm + mi * 16 + q * 4 + r;
      int tok = rtok[orow];
      float w = rw[orow];
      if (w != 0.f) {
#pragma unroll
        for (int ni = 0; ni < 4; ni++) {
          int n = nbase + ni * 16 + lrow;
          if (n < H_DIM) atomicAdd(&out[tok * H_DIM + n], w * (acc[mi][ni][r] + bias_v[ni]));
        }
      }
    }
}

extern "C" void kernel_launch(void* const* d_in, const int* in_sizes, int n_in,
                              void* d_out, int out_size, void* d_ws, size_t ws_size,
                              hipStream_t stream) {
  const float* hs = (const float*)d_in[0];
  const int* eidx = (const int*)d_in[1];
  const float* rwt = (const float*)d_in[2];
  const int* gub = (const int*)d_in[3];
  const int* gus = (const int*)d_in[4];
  const float* gubias = (const float*)d_in[5];
  const int* db = (const int*)d_in[6];
  const int* dsc = (const int*)d_in[7];
  const float* dbias = (const float*)d_in[8];
  float* out = (float*)d_out;
  char* ws = (char*)d_ws;

  ushort* xq = (ushort*)(ws + XQ_OFF);
  ushort* act = (ushort*)(ws + ACT_OFF);
  int* rtok = (int*)(ws + RTOK_OFF);
  float* rw = (float*)(ws + RW_OFF);
  int* ebase = (int*)(ws + EB_OFF);
  int* epc = (int*)(ws + EPC_OFF);

  hipMemsetAsync(d_out, 0, (size_t)out_size * sizeof(float), stream);
  quant_x_kernel<<<2880, 256, 0, stream>>>(hs, xq);
  routing_kernel<<<1, 256, 0, stream>>>(eidx, rwt, rtok, rw, ebase, epc);
  gemm1_kernel<<<dim3(45, 128), 256, 0, stream>>>(xq, gub, gus, gubias, rtok, ebase, epc, act);
  gemm2_kernel<<<dim3(23, 128), 256, 0, stream>>>(act, db, dsc, dbias, rtok, rw, ebase, epc, out);
}

// Round 2
// 810.354 us; speedup vs baseline: 1.1383x; 1.1383x over previous
//
#include <hip/hip_runtime.h>
#include <math.h>

#define T_TOK 1024
#define E_EXP 8
#define H_DIM 2880
#define I_DIM 2880
#define NGU   5760      // 2*I
#define KB    90        // 2880/32
#define TM 128
#define TN 128
#define MAXROWS 3072

typedef __attribute__((ext_vector_type(8))) short short8;
typedef __attribute__((ext_vector_type(4))) float f32x4;

// ---- workspace layout (bytes) ----
#define XQ_OFF   0ull                    // T*H bf16 = 5898240
#define ACT_OFF  5898240ull              // MAXROWS*I bf16 = 17694720
#define RTOK_OFF 23592960ull             // MAXROWS int
#define RW_OFF   23605248ull             // MAXROWS float
#define EB_OFF   23617536ull             // 8 int
#define EPC_OFF  23617600ull             // 8 int

__device__ inline ushort f2bf(float f) {
  unsigned u = __float_as_uint(f);
  unsigned r = u + 0x7FFFu + ((u >> 16) & 1u);
  return (ushort)(r >> 16);
}

// e = clip(ceil(log2(max(amax,1e-12))), -127, 128)
__device__ inline int blk_exp(float amax) {
  amax = fmaxf(amax, 1e-12f);
  unsigned b = __float_as_uint(amax);
  int e = (int)(b >> 23) - 127;
  if (b & 0x7FFFFFu) e += 1;
  return min(max(e, -127), 128);
}

// quantize v*2^-eblk to fp8 e4m3 (RNE, subnormal lsb 2^-9), dequantize back.
__device__ inline float qdq_val(float v, int eblk) {
  float av = fabsf(v);
  if (av == 0.f) return 0.f;
  int fl = (int)(__float_as_uint(av) >> 23) - 127 - eblk;  // floor(log2|v/2^eblk|)
  int p = max(fl, -6) - 3;
  float step = ldexpf(1.f, p + eblk);
  return rintf(v / step) * step;
}

__device__ inline float fp4v(int n) {
  int mag = n & 7;
  float v;
  if (mag == 0) v = 0.f;
  else if (mag == 1) v = 0.5f;
  else v = ldexpf(1.0f + 0.5f * (float)(mag & 1), (mag >> 1) - 1);
  return (n & 8) ? -v : v;
}

// decode one weight byte (2 fp4) * scale -> packed bf16 pair.
// exact products => bf16 = f32 truncation; pack via v_perm.
__device__ inline uint dec_byte(const float2* lut, int b, float sc) {
  float2 l = lut[b & 255];
  uint lo = __float_as_uint(l.x * sc);
  uint hi = __float_as_uint(l.y * sc);
  return __builtin_amdgcn_perm(hi, lo, 0x07060302u);
}

// ---------------- kernel 1: mxfp8 qdq of hidden_states -> bf16 ----------------
__global__ void quant_x_kernel(const float* __restrict__ x, ushort* __restrict__ xq) {
  int g = blockIdx.x * 256 + threadIdx.x;   // 737280 threads total, exact
  float4 v4 = ((const float4*)x)[g];
  float am = fmaxf(fmaxf(fabsf(v4.x), fabsf(v4.y)), fmaxf(fabsf(v4.z), fabsf(v4.w)));
  am = fmaxf(am, __shfl_xor(am, 1));
  am = fmaxf(am, __shfl_xor(am, 2));
  am = fmaxf(am, __shfl_xor(am, 4));
  int eb = blk_exp(am);
  ushort4 o;
  o.x = f2bf(qdq_val(v4.x, eb));
  o.y = f2bf(qdq_val(v4.y, eb));
  o.z = f2bf(qdq_val(v4.z, eb));
  o.w = f2bf(qdq_val(v4.w, eb));
  ((ushort4*)xq)[g] = o;
}

// ---------------- kernel 2: routing -> per-expert padded row lists ----------------
__global__ void routing_kernel(const int* __restrict__ eidx, const float* __restrict__ rwt,
                               int* __restrict__ rtok, float* __restrict__ rw,
                               int* __restrict__ ebase, int* __restrict__ epc) {
  __shared__ int cnt[E_EXP];
  __shared__ int base_s[E_EXP];
  __shared__ int pos[E_EXP];
  int t = threadIdx.x;
  if (t < E_EXP) cnt[t] = 0;
  __syncthreads();
  for (int p = t; p < T_TOK * 2; p += 256) atomicAdd(&cnt[eidx[p]], 1);
  __syncthreads();
  if (t == 0) {
    int b = 0;
    for (int e = 0; e < E_EXP; e++) {
      base_s[e] = b;
      b += ((cnt[e] + TM - 1) / TM) * TM;
    }
  }
  __syncthreads();
  if (t < E_EXP) {
    pos[t] = 0;
    ebase[t] = base_s[t];
    epc[t] = ((cnt[t] + TM - 1) / TM) * TM;
  }
  __syncthreads();
  for (int p = t; p < T_TOK * 2; p += 256) {
    int e = eidx[p];
    int o = atomicAdd(&pos[e], 1);
    rtok[base_s[e] + o] = p >> 1;
    rw[base_s[e] + o] = rwt[p];
  }
  __syncthreads();
  for (int e = 0; e < E_EXP; e++) {
    int c = cnt[e], pc = ((c + TM - 1) / TM) * TM;
    for (int i = c + t; i < pc; i += 256) {
      rtok[base_s[e] + i] = 0;
      rw[base_s[e] + i] = 0.f;
    }
  }
}

// ---------------- kernel 3: GEMM1 (xq @ Wgu^T + b) -> swiglu -> qdq -> act ----------------
__global__ __launch_bounds__(256, 2)
void gemm1_kernel(const ushort* __restrict__ xq,
                  const int* __restrict__ gub, const int* __restrict__ gus,
                  const float* __restrict__ gubias,
                  const int* __restrict__ rtok, const int* __restrict__ ebase,
                  const int* __restrict__ epc,
                  ushort* __restrict__ act) {
  const int ntile = blockIdx.x;           // 0..44
  const int e = blockIdx.y >> 4;
  const int mtile = blockIdx.y & 15;
  if (mtile * TM >= epc[e]) return;
  const int rowbase = ebase[e] + mtile * TM;

  __shared__ __align__(16) ushort lA[TM][40];   // +8 pad: conflict-free b128, 16B-aligned rows
  __shared__ __align__(16) ushort lB[TN][40];
  __shared__ float2 lut[256];

  const int tid = threadIdx.x;
  lut[tid] = make_float2(fp4v(tid & 15), fp4v((tid >> 4) & 15));
  __syncthreads();

  const int wave = tid >> 6, lane = tid & 63;
  const int half = tid & 1, srow = tid >> 1;
  const int wm = (wave & 1) * 64, wn = (wave >> 1) * 64;
  const int lrow = lane & 15, q = lane >> 4;

  const int tokA = rtok[rowbase + srow];
  const ushort* aSrc = xq + tokA * H_DIM + half * 16;
  const int nrow = ntile * TN + srow;                       // < 5760 always
  const int* bSrc = gub + ((e * NGU + nrow) * KB) * 16 + half * 8;
  const int* sSrc = gus + (e * NGU + nrow) * KB;

  f32x4 acc[4][4];
#pragma unroll
  for (int i = 0; i < 4; i++)
#pragma unroll
    for (int j = 0; j < 4; j++) acc[i][j] = (f32x4){0.f, 0.f, 0.f, 0.f};

  // software pipeline: prologue load of kb=0
  uint4 a0 = ((const uint4*)(aSrc))[0];
  uint4 a1 = ((const uint4*)(aSrc))[1];
  int4 b0 = ((const int4*)(bSrc))[0];
  int4 b1 = ((const int4*)(bSrc))[1];
  int sraw = sSrc[0];

  for (int kb = 0; kb < KB; kb++) {
    // issue prefetch for kb+1 (clamped) — stays in flight across this iteration
    const int nk = (kb + 1 < KB) ? kb + 1 : kb;
    uint4 na0 = ((const uint4*)(aSrc + nk * 32))[0];
    uint4 na1 = ((const uint4*)(aSrc + nk * 32))[1];
    int4 nb0 = ((const int4*)(bSrc + nk * 16))[0];
    int4 nb1 = ((const int4*)(bSrc + nk * 16))[1];
    int nsraw = sSrc[nk];

    float sc = ldexpf(1.f, sraw - 127);
    uint us[8];
    us[0] = dec_byte(lut, b0.x, sc);
    us[1] = dec_byte(lut, b0.y, sc);
    us[2] = dec_byte(lut, b0.z, sc);
    us[3] = dec_byte(lut, b0.w, sc);
    us[4] = dec_byte(lut, b1.x, sc);
    us[5] = dec_byte(lut, b1.y, sc);
    us[6] = dec_byte(lut, b1.z, sc);
    us[7] = dec_byte(lut, b1.w, sc);

    __syncthreads();
    *(uint4*)&lA[srow][half * 16] = a0;
    *(uint4*)&lA[srow][half * 16 + 8] = a1;
    uint4 w0; w0.x = us[0]; w0.y = us[1]; w0.z = us[2]; w0.w = us[3];
    uint4 w1; w1.x = us[4]; w1.y = us[5]; w1.z = us[6]; w1.w = us[7];
    *(uint4*)&lB[srow][half * 16] = w0;
    *(uint4*)&lB[srow][half * 16 + 8] = w1;
    __syncthreads();

    short8 af[4], bfr[4];
#pragma unroll
    for (int mi = 0; mi < 4; mi++) af[mi] = *(const short8*)&lA[wm + mi * 16 + lrow][q * 8];
#pragma unroll
    for (int ni = 0; ni < 4; ni++) bfr[ni] = *(const short8*)&lB[wn + ni * 16 + lrow][q * 8];
#pragma unroll
    for (int mi = 0; mi < 4; mi++)
#pragma unroll
      for (int ni = 0; ni < 4; ni++)
        acc[mi][ni] = __builtin_amdgcn_mfma_f32_16x16x32_bf16(af[mi], bfr[ni], acc[mi][ni], 0, 0, 0);

    a0 = na0; a1 = na1; b0 = nb0; b1 = nb1; sraw = nsraw;
  }

  // epilogue: bias -> swiglu (even n = gate, odd n = up) -> per-32-channel mxfp8 qdq -> act bf16
  const int nbase = ntile * TN + wn;
  float bias_v[4];
#pragma unroll
  for (int ni = 0; ni < 4; ni++) bias_v[ni] = gubias[e * NGU + nbase + ni * 16 + lrow];
  const bool evenl = (lane & 1) == 0;
#pragma unroll
  for (int mi = 0; mi < 4; mi++) {
    float av[4][4];
#pragma unroll
    for (int ni = 0; ni < 4; ni++)
#pragma unroll
      for (int r = 0; r < 4; r++) {
        float h = acc[mi][ni][r] + bias_v[ni];
        float pp = __shfl_xor(h, 1);
        float gate = evenl ? h : pp;
        float up = evenl ? pp : h;
        gate = fminf(gate, 7.f);
        up = fminf(fmaxf(up, -7.f), 7.f);
        float glu = gate / (1.f + expf(-1.702f * gate));
        av[ni][r] = (up + 1.f) * glu;
      }
#pragma unroll
    for (int r = 0; r < 4; r++) {
      float am = 0.f;
#pragma unroll
      for (int ni = 0; ni < 4; ni++) am = fmaxf(am, fabsf(av[ni][r]));
      am = fmaxf(am, __shfl_xor(am, 2));
      am = fmaxf(am, __shfl_xor(am, 4));
      am = fmaxf(am, __shfl_xor(am, 8));
      int eb = blk_exp(am);
      if (evenl) {
        int row = rowbase + wm + mi * 16 + q * 4 + r;
        int cb = (nbase >> 1) + (lrow >> 1);
#pragma unroll
        for (int ni = 0; ni < 4; ni++)
          act[row * I_DIM + cb + ni * 8] = f2bf(qdq_val(av[ni][r], eb));
      }
    }
  }
}

// ---------------- kernel 4: GEMM2 (act @ Wd^T + b) * routing_weight -> atomic scatter ----------------
// K-split over blockIdx.z (2 halves of KB) for 2x grid parallelism.
__global__ __launch_bounds__(256, 2)
void gemm2_kernel(const ushort* __restrict__ act,
                  const int* __restrict__ db, const int* __restrict__ dsc,
                  const float* __restrict__ dbias,
                  const int* __restrict__ rtok, const float* __restrict__ rw,
                  const int* __restrict__ ebase, const int* __restrict__ epc,
                  float* __restrict__ out) {
  const int ntile = blockIdx.x;           // 0..22
  const int e = blockIdx.y >> 4;
  const int mtile = blockIdx.y & 15;
  if (mtile * TM >= epc[e]) return;
  const int rowbase = ebase[e] + mtile * TM;
  const int kz = blockIdx.z;              // 0 or 1
  const int kb0 = kz * (KB / 2), kb1 = kb0 + (KB / 2);

  __shared__ __align__(16) ushort lA[TM][40];
  __shared__ __align__(16) ushort lB[TN][40];
  __shared__ float2 lut[256];

  const int tid = threadIdx.x;
  lut[tid] = make_float2(fp4v(tid & 15), fp4v((tid >> 4) & 15));
  __syncthreads();

  const int wave = tid >> 6, lane = tid & 63;
  const int half = tid & 1, srow = tid >> 1;
  const int wm = (wave & 1) * 64, wn = (wave >> 1) * 64;
  const int lrow = lane & 15, q = lane >> 4;

  const ushort* aSrc = act + (rowbase + srow) * I_DIM + half * 16;
  int nrow = ntile * TN + srow;
  if (nrow >= H_DIM) nrow = H_DIM - 1;    // clamp loads; stores guarded
  const int* bSrc = db + ((e * H_DIM + nrow) * KB) * 16 + half * 8;
  const int* sSrc = dsc + (e * H_DIM + nrow) * KB;

  f32x4 acc[4][4];
#pragma unroll
  for (int i = 0; i < 4; i++)
#pragma unroll
    for (int j = 0; j < 4; j++) acc[i][j] = (f32x4){0.f, 0.f, 0.f, 0.f};

  uint4 a0 = ((const uint4*)(aSrc + kb0 * 32))[0];
  uint4 a1 = ((const uint4*)(aSrc + kb0 * 32))[1];
  int4 b0 = ((const int4*)(bSrc + kb0 * 16))[0];
  int4 b1 = ((const int4*)(bSrc + kb0 * 16))[1];
  int sraw = sSrc[kb0];

  for (int kb = kb0; kb < kb1; kb++) {
    const int nk = (kb + 1 < kb1) ? kb + 1 : kb;
    uint4 na0 = ((const uint4*)(aSrc + nk * 32))[0];
    uint4 na1 = ((const uint4*)(aSrc + nk * 32))[1];
    int4 nb0 = ((const int4*)(bSrc + nk * 16))[0];
    int4 nb1 = ((const int4*)(bSrc + nk * 16))[1];
    int nsraw = sSrc[nk];

    float sc = ldexpf(1.f, sraw - 127);
    uint us[8];
    us[0] = dec_byte(lut, b0.x, sc);
    us[1] = dec_byte(lut, b0.y, sc);
    us[2] = dec_byte(lut, b0.z, sc);
    us[3] = dec_byte(lut, b0.w, sc);
    us[4] = dec_byte(lut, b1.x, sc);
    us[5] = dec_byte(lut, b1.y, sc);
    us[6] = dec_byte(lut, b1.z, sc);
    us[7] = dec_byte(lut, b1.w, sc);

    __syncthreads();
    *(uint4*)&lA[srow][half * 16] = a0;
    *(uint4*)&lA[srow][half * 16 + 8] = a1;
    uint4 w0; w0.x = us[0]; w0.y = us[1]; w0.z = us[2]; w0.w = us[3];
    uint4 w1; w1.x = us[4]; w1.y = us[5]; w1.z = us[6]; w1.w = us[7];
    *(uint4*)&lB[srow][half * 16] = w0;
    *(uint4*)&lB[srow][half * 16 + 8] = w1;
    __syncthreads();

    short8 af[4], bfr[4];
#pragma unroll
    for (int mi = 0; mi < 4; mi++) af[mi] = *(const short8*)&lA[wm + mi * 16 + lrow][q * 8];
#pragma unroll
    for (int ni = 0; ni < 4; ni++) bfr[ni] = *(const short8*)&lB[wn + ni * 16 + lrow][q * 8];
#pragma unroll
    for (int mi = 0; mi < 4; mi++)
#pragma unroll
      for (int ni = 0; ni < 4; ni++)
        acc[mi][ni] = __builtin_amdgcn_mfma_f32_16x16x32_bf16(af[mi], bfr[ni], acc[mi][ni], 0, 0, 0);

    a0 = na0; a1 = na1; b0 = nb0; b1 = nb1; sraw = nsraw;
  }

  const int nbase = ntile * TN + wn;
  float bias_v[4];
#pragma unroll
  for (int ni = 0; ni < 4; ni++) {
    int n = nbase + ni * 16 + lrow;
    bias_v[ni] = (kz == 0 && n < H_DIM) ? dbias[e * H_DIM + n] : 0.f;
  }
#pragma unroll
  for (int mi = 0; mi < 4; mi++)
#pragma unroll
    for (int r = 0; r < 4; r++) {
      int orow = rowbase + wm + mi * 16 + q * 4 + r;
      int tok = rtok[orow];
      float w = rw[orow];
      if (w != 0.f) {
#pragma unroll
        for (int ni = 0; ni < 4; ni++) {
          int n = nbase + ni * 16 + lrow;
          if (n < H_DIM) atomicAdd(&out[tok * H_DIM + n], w * (acc[mi][ni][r] + bias_v[ni]));
        }
      }
    }
}

extern "C" void kernel_launch(void* const* d_in, const int* in_sizes, int n_in,
                              void* d_out, int out_size, void* d_ws, size_t ws_size,
                              hipStream_t stream) {
  const float* hs = (const float*)d_in[0];
  const int* eidx = (const int*)d_in[1];
  const float* rwt = (const float*)d_in[2];
  const int* gub = (const int*)d_in[3];
  const int* gus = (const int*)d_in[4];
  const float* gubias = (const float*)d_in[5];
  const int* db = (const int*)d_in[6];
  const int* dsc = (const int*)d_in[7];
  const float* dbias = (const float*)d_in[8];
  float* out = (float*)d_out;
  char* ws = (char*)d_ws;

  ushort* xq = (ushort*)(ws + XQ_OFF);
  ushort* act = (ushort*)(ws + ACT_OFF);
  int* rtok = (int*)(ws + RTOK_OFF);
  float* rw = (float*)(ws + RW_OFF);
  int* ebase = (int*)(ws + EB_OFF);
  int* epc = (int*)(ws + EPC_OFF);

  hipMemsetAsync(d_out, 0, (size_t)out_size * sizeof(float), stream);
  quant_x_kernel<<<2880, 256, 0, stream>>>(hs, xq);
  routing_kernel<<<1, 256, 0, stream>>>(eidx, rwt, rtok, rw, ebase, epc);
  gemm1_kernel<<<dim3(45, 128), 256, 0, stream>>>(xq, gub, gus, gubias, rtok, ebase, epc, act);
  gemm2_kernel<<<dim3(23, 128, 2), 256, 0, stream>>>(act, db, dsc, dbias, rtok, rw, ebase, epc, out);
}